// Round 5
// baseline (3796.804 us; speedup 1.0000x reference)
//
#include <hip/hip_runtime.h>
#include <stdint.h>

// LSTMClassifier on MI355X — round 17: B-fragments in VGPRs for real.
// R16 counters: SQ_LDS_BANK_CONFLICT 9.4M (xbuf stride-64B layout) and the
// structural 4x duplication of B-fragment LDS reads (384 ds_read_b128/step/CU
// = 4600cy, the largest pipe cost). R14's register attempt failed because the
// quadrant split needs 384 VGPRs of B per wave. Fix: wave = (row-pair r2,
// gate-pair c2, K-half ks): B share = 2 gates x 12 K-chunks = 24 frags =
// 96 VGPRs — fits (total ~200 < 256 @ 2 waves/SIMD). Zero in-loop LDS for B.
//   - A-frags (e,h) from global: 24/wave/step, 2x dup across c2 -> L1 hits
//     (dup pair is barrier-lockstepped).
//   - Partial-sum exchange via conflict-free LDS layout [s][w][lane][4]
//     (lane stride 16B). Epilogue split across ALL 8 waves (r-pairs).
//   - Sync skeleton unchanged (proven R15/R16): wave0 relaxed-agent poll,
//     3 barriers, single relaxed-agent publish, bounded RMW fallback.
//
// Workspace (50.6 MiB): unchanged layout.

#define EMB   256
#define HID   512
#define NOUT  18
#define BATCH 64
#define SEQ   512
#define NPART 32     // scan workgroups = CUs on one XCD
#define WCOLS 16     // h-cols per wg (512/32)

typedef __attribute__((ext_vector_type(8))) short bf16x8;
typedef __attribute__((ext_vector_type(4))) float floatx4;
typedef __attribute__((ext_vector_type(2))) float floatx2;

__device__ inline float bf2f(short u) {
    union { float f; uint32_t i; } v;
    v.i = ((uint32_t)(uint16_t)u) << 16;
    return v.f;
}
__device__ inline short f2bf(float f) {
    union { float f; uint32_t i; } v; v.f = f;
    uint32_t r = v.i + 0x7fffu + ((v.i >> 16) & 1u);   // RNE
    return (short)(r >> 16);
}
__device__ inline float sigm(float x) { return 1.f / (1.f + __expf(-x)); }
__device__ inline float tanh_fast(float x) {
    float xc = fminf(fmaxf(x, -15.f), 15.f);
    float e  = __expf(2.f * xc);
    return (e - 1.f) / (e + 1.f);
}

// Detect packed-bf16 vs fp32 float tensors (verified round 4 — keep).
__device__ inline bool detect_bf16(const void* emb_raw) {
    const uint32_t* w = (const uint32_t*)emb_raw;
    int votes = 0;
    #pragma unroll
    for (int i = 0; i < 8; i++) {
        uint32_t e = (w[i] >> 7) & 0xFFu;
        votes += (e >= 110u && e <= 135u) ? 1 : 0;
    }
    return votes >= 6;
}
__device__ inline float rd(const void* p, int idx, bool isbf) {
    return isbf ? bf2f(((const short*)p)[idx]) : ((const float*)p)[idx];
}

// load one 8-element bf16 fragment from a maybe-fp32 weight row
__device__ inline bf16x8 ldfrag(const void* base, size_t off, bool isbf) {
    if (isbf) return *(const bf16x8*)((const short*)base + off);
    const float* s = (const float*)base + off;
    bf16x8 v;
    #pragma unroll
    for (int j = 0; j < 8; j++) v[j] = f2bf(s[j]);
    return v;
}

// ---------------------------------------------------------------------------
// K0: e_seq[u][k] = emb[x[u&63][u>>6]][k] (bf16 out), u = s*64+b.
// ---------------------------------------------------------------------------
__global__ __launch_bounds__(256) void k0_gather(
    const int* __restrict__ x, const void* __restrict__ emb,
    short* __restrict__ eseq)
{
    const bool isbf = detect_bf16(emb);
    const int u0 = blockIdx.x * 32;
    #pragma unroll
    for (int it = 0; it < 4; it++) {
        int idx = it * 256 + threadIdx.x;          // 0..1023
        int u   = u0 + (idx >> 5);
        int ch  = (idx & 31) * 8;
        int tok = x[(u & 63) * SEQ + (u >> 6)];
        bf16x8 v;
        if (isbf) {
            v = *(const bf16x8*)((const short*)emb + (size_t)tok * EMB + ch);
        } else {
            const float* src = (const float*)emb + (size_t)tok * EMB + ch;
            #pragma unroll
            for (int j = 0; j < 8; j++) v[j] = f2bf(src[j]);
        }
        *(bf16x8*)(eseq + (size_t)u * EMB + ch) = v;
    }
}

// ---------------------------------------------------------------------------
// K2: intra-XCD persistent scan. B-frags in VGPRs (96/wave). 32 wgs of 512
// threads. Wave w: r2=w&1 (rows 32), c2=(w>>1)&1 (gate pair), ks=w>>2 (K half).
// ---------------------------------------------------------------------------
__global__ __launch_bounds__(512, 2) void k2_lstm(
    const void* __restrict__ w_hh, const void* __restrict__ w_ih,
    const void* __restrict__ b_ih, const void* __restrict__ b_hh,
    const void* __restrict__ emb, const short* __restrict__ eseq,
    short* __restrict__ hbuf, int* __restrict__ sync, int* __restrict__ flags)
{
    // partial-sum exchange: [s(4)][w(8)][lane(64)][4 f32] = 32KB.
    // lane stride 16B -> conflict-free b128 writes/reads.
    __shared__ float xbuf[4 * 8 * 64 * 4];
    __shared__ float biasl[64];
    __shared__ int   sh_slot;

    const int t = threadIdx.x;

    // ---- XCD leader claim (round-9/10 verified; startup only).
    // Pigeonhole: 8*31 = 248 < 256 grid => some XCD always reaches NPART. ----
    if (t == 0) {
        unsigned xcd;
        asm volatile("s_getreg_b32 %0, hwreg(HW_REG_XCC_ID)" : "=s"(xcd));
        xcd &= 7u;
        int c = atomicAdd(&sync[8 + xcd], 1);
        if (c == NPART - 1) atomicCAS(&sync[0], 0, (int)xcd + 1);
        int L;
        while ((L = atomicAdd(&sync[0], 0)) == 0)
            __builtin_amdgcn_s_sleep(8);
        sh_slot = (L == (int)xcd + 1 && c < NPART) ? c : -1;
    }
    __syncthreads();
    const int g = sh_slot;
    if (g < 0) return;

    const bool isbf = detect_bf16(emb);
    const int lane = t & 63;
    const int w    = t >> 6;        // 0..7
    const int r2   = w & 1;         // row half (rows r2*32..+32)
    const int c2   = (w >> 1) & 1;  // gate pair {2c2, 2c2+1}
    const int ks   = w >> 2;        // K half
    const int col  = lane & 15;
    const int quad = lane >> 4;

    // ---- B fragments to REGISTERS: 24 frags = 96 VGPRs (fits; R14's 384
    // did not, which is why the compiler sank those loads). ----
    bf16x8 bh[2][8], be[2][4];
    #pragma unroll
    for (int ntl = 0; ntl < 2; ntl++) {
        const size_t grow = (size_t)((2 * c2 + ntl) * HID + g * WCOLS + col);
        #pragma unroll
        for (int kk = 0; kk < 8; kk++)
            bh[ntl][kk] = ldfrag(w_hh, grow * HID + (size_t)(ks * 8 + kk) * 32 + quad * 8, isbf);
        #pragma unroll
        for (int kk = 0; kk < 4; kk++)
            be[ntl][kk] = ldfrag(w_ih, grow * EMB + (size_t)(ks * 4 + kk) * 32 + quad * 8, isbf);
    }
    if (t < 64) {
        int grow = (t >> 4) * HID + g * WCOLS + (t & 15);
        biasl[t] = rd(b_ih, grow, isbf) + rd(b_hh, grow, isbf);
    }
    __syncthreads();

    // epilogue role: quadrant q = w&3, row-pair roff = (w>>2)*2
    const int q    = w & 3;
    const int roff = (w >> 2) * 2;
    const float bI = biasl[col],      bF = biasl[16 + col];
    const float bG = biasl[32 + col], bO = biasl[48 + col];

    float cre[2] = {0.f, 0.f};

    const short* eptr0 = eseq + (size_t)((2 * r2) * 16 + col) * EMB + quad * 8;
    const short* eptr1 = eptr0 + (size_t)16 * EMB;
    const short* hrd0  = hbuf + (size_t)((2 * r2) * 16 + col) * HID + quad * 8;
    const short* hrd1  = hrd0 + (size_t)16 * HID;
    short*       hwr   = hbuf + (size_t)(BATCH * HID)
                       + (size_t)(q * 16 + quad * 4 + roff) * HID + g * WCOLS + col;

    // ---- scan ----
    for (int step = 0; step < SEQ; step++) {
        // e A-frags + e-projection MFMAs (handshake-independent, pre-poll)
        bf16x8 ae0[4], ae1[4];
        #pragma unroll
        for (int kk = 0; kk < 4; kk++) {
            ae0[kk] = *(const bf16x8*)(eptr0 + (ks * 4 + kk) * 32);
            ae1[kk] = *(const bf16x8*)(eptr1 + (ks * 4 + kk) * 32);
        }

        floatx4 a00 = (floatx4){0.f,0.f,0.f,0.f}, a01 = a00, a10 = a00, a11 = a00;
        #pragma unroll
        for (int kk = 0; kk < 4; kk++) {
            a00 = __builtin_amdgcn_mfma_f32_16x16x32_bf16(ae0[kk], be[0][kk], a00, 0,0,0);
            a01 = __builtin_amdgcn_mfma_f32_16x16x32_bf16(ae0[kk], be[1][kk], a01, 0,0,0);
            a10 = __builtin_amdgcn_mfma_f32_16x16x32_bf16(ae1[kk], be[0][kk], a10, 0,0,0);
            a11 = __builtin_amdgcn_mfma_f32_16x16x32_bf16(ae1[kk], be[1][kk], a11, 0,0,0);
        }

        // wave0's lanes 0..31 poll the 32 producer flags (RELAXED agent =
        // sc1 L1-bypass, no buffer_inv). Other waves wait at the barrier.
        if (step > 0 && w == 0 && lane < NPART) {
            int* fp = flags + (size_t)step * 64 + lane;
            int iters = 0;
            while (__hip_atomic_load(fp, __ATOMIC_RELAXED,
                                     __HIP_MEMORY_SCOPE_AGENT) == 0) {
                if (++iters > 16384) {
                    while (atomicAdd(fp, 0) == 0)
                        __builtin_amdgcn_s_sleep(8);
                    break;
                }
            }
        }
        __builtin_amdgcn_sched_barrier(0);
        __syncthreads();       // h(step-1) published & in L2

        // h A-frags (this wave's K-half), both row-tiles back-to-back
        bf16x8 ah0[8], ah1[8];
        #pragma unroll
        for (int kk = 0; kk < 8; kk++) {
            ah0[kk] = *(const bf16x8*)(hrd0 + (ks * 8 + kk) * 32);
            ah1[kk] = *(const bf16x8*)(hrd1 + (ks * 8 + kk) * 32);
        }
        #pragma unroll
        for (int kk = 0; kk < 8; kk++) {
            a00 = __builtin_amdgcn_mfma_f32_16x16x32_bf16(ah0[kk], bh[0][kk], a00, 0,0,0);
            a01 = __builtin_amdgcn_mfma_f32_16x16x32_bf16(ah0[kk], bh[1][kk], a01, 0,0,0);
            a10 = __builtin_amdgcn_mfma_f32_16x16x32_bf16(ah1[kk], bh[0][kk], a10, 0,0,0);
            a11 = __builtin_amdgcn_mfma_f32_16x16x32_bf16(ah1[kk], bh[1][kk], a11, 0,0,0);
        }

        // export partials: s = rt*2+ntl, slot w, lane-contiguous (no conflicts)
        *(floatx4*)&xbuf[(((size_t)0 * 8 + w) * 64 + lane) * 4] = a00;
        *(floatx4*)&xbuf[(((size_t)1 * 8 + w) * 64 + lane) * 4] = a01;
        *(floatx4*)&xbuf[(((size_t)2 * 8 + w) * 64 + lane) * 4] = a10;
        *(floatx4*)&xbuf[(((size_t)3 * 8 + w) * 64 + lane) * 4] = a11;
        __syncthreads();       // partials visible

        // epilogue: ALL 8 waves; wave w does rows {roff, roff+1} of quadrant q.
        {
            floatx2 tot[4];
            #pragma unroll
            for (int nt = 0; nt < 4; nt++) {
                const int s  = (q & 1) * 2 + (nt & 1);
                const int wa = 0 * 4 + (nt >> 1) * 2 + (q >> 1);
                const int wb = 1 * 4 + (nt >> 1) * 2 + (q >> 1);
                floatx2 pa = *(const floatx2*)&xbuf[(((size_t)s * 8 + wa) * 64 + lane) * 4 + roff];
                floatx2 pb = *(const floatx2*)&xbuf[(((size_t)s * 8 + wb) * 64 + lane) * 4 + roff];
                tot[nt] = pa + pb;
            }
            #pragma unroll
            for (int rs = 0; rs < 2; rs++) {
                float iv = sigm(tot[0][rs] + bI);
                float fv = sigm(tot[1][rs] + bF);
                float gv = tanh_fast(tot[2][rs] + bG);
                float ov = sigm(tot[3][rs] + bO);
                cre[rs] = fv * cre[rs] + iv * gv;
                hwr[(size_t)rs * HID] = f2bf(ov * tanh_fast(cre[rs]));
            }
        }

        // barrier drains every wave's vmcnt before s_barrier => all h-stores
        // committed to L2 when t0 publishes.
        __syncthreads();
        if (t == 0)
            __hip_atomic_store(flags + (size_t)(step + 1) * 64 + g, 1,
                               __ATOMIC_RELAXED, __HIP_MEMORY_SCOPE_AGENT);

        eptr0 += (size_t)BATCH * EMB;
        eptr1 += (size_t)BATCH * EMB;
        hrd0  += (size_t)BATCH * HID;
        hrd1  += (size_t)BATCH * HID;
        hwr   += (size_t)BATCH * HID;
    }
}

// ---------------------------------------------------------------------------
// K3: logits = h_seq * W_fc^T + b_fc -> log_softmax(18). One token per thread.
// ---------------------------------------------------------------------------
__global__ __launch_bounds__(256) void k3_logits(
    const short* __restrict__ hbuf, const void* __restrict__ w_fc,
    const void* __restrict__ b_fc, const void* __restrict__ emb,
    void* __restrict__ out)
{
    __shared__ float Wf[NOUT][516];
    const bool isbf = detect_bf16(emb);
    const int t = threadIdx.x;
    for (int idx = t; idx < NOUT * 64; idx += 256) {
        int o = idx >> 6, ch = (idx & 63) * 8;
        #pragma unroll
        for (int j = 0; j < 8; j++)
            Wf[o][ch + j] = rd(w_fc, o * HID + ch + j, isbf);
    }
    __syncthreads();

    int u = blockIdx.x * 256 + t;              // u = s*64+b
    const short* hp = hbuf + (size_t)(u + BATCH) * HID;

    float acc[NOUT];
    #pragma unroll
    for (int o = 0; o < NOUT; o++) acc[o] = rd(b_fc, o, isbf);

    for (int ch = 0; ch < HID; ch += 8) {
        bf16x8 h8 = *(const bf16x8*)(hp + ch);
        float hf[8];
        #pragma unroll
        for (int j = 0; j < 8; j++) hf[j] = bf2f(h8[j]);
        #pragma unroll
        for (int o = 0; o < NOUT; o++) {
            floatx4 wa = *(const floatx4*)&Wf[o][ch];
            floatx4 wb = *(const floatx4*)&Wf[o][ch + 4];
            acc[o] += hf[0] * wa[0] + hf[1] * wa[1] + hf[2] * wa[2] + hf[3] * wa[3]
                    + hf[4] * wb[0] + hf[5] * wb[1] + hf[6] * wb[2] + hf[7] * wb[3];
        }
    }

    float mx = acc[0];
    #pragma unroll
    for (int o = 1; o < NOUT; o++) mx = fmaxf(mx, acc[o]);
    float s = 0.f;
    #pragma unroll
    for (int o = 0; o < NOUT; o++) s += __expf(acc[o] - mx);
    float lse = mx + __logf(s);

    int b = u & 63, sq = u >> 6;
    size_t base = (size_t)b * (SEQ * NOUT) + (size_t)sq * NOUT;
    if (isbf) {
        short* op = (short*)out + base;
        #pragma unroll
        for (int o = 0; o < NOUT; o++) op[o] = f2bf(acc[o] - lse);
    } else {
        float* op = (float*)out + base;
        #pragma unroll
        for (int o = 0; o < NOUT; o++) op[o] = acc[o] - lse;
    }
}

// ---------------------------------------------------------------------------
extern "C" void kernel_launch(void* const* d_in, const int* in_sizes, int n_in,
                              void* d_out, int out_size, void* d_ws, size_t ws_size,
                              hipStream_t stream) {
    const int*  x   = (const int*)d_in[0];
    const void* emb = d_in[1];
    const void* wih = d_in[2];
    const void* whh = d_in[3];
    const void* bih = d_in[4];
    const void* bhh = d_in[5];
    const void* wfc = d_in[6];
    const void* bfc = d_in[7];

    char*  ws    = (char*)d_ws;
    int*   sync  = (int*)ws;
    int*   flags = (int*)(ws + 4096);
    const size_t flagsz = (size_t)(SEQ + 1) * 64 * sizeof(int);   // 131.3 KB
    short* hbuf  = (short*)(ws + 4096 + ((flagsz + 255) & ~(size_t)255));
    short* eseq  = (short*)((char*)hbuf + (size_t)(SEQ + 1) * BATCH * HID * 2);

    (void)hipMemsetAsync(sync, 0, 4096, stream);                    // claim
    (void)hipMemsetAsync(flags, 0, flagsz, stream);                 // flags = 0
    (void)hipMemsetAsync(hbuf, 0, (size_t)BATCH * HID * 2, stream); // h_0 = 0

    k0_gather<<<1024, 256, 0, stream>>>(x, emb, eseq);
    k2_lstm<<<256, 512, 0, stream>>>(whh, wih, bih, bhh, emb, eseq,
                                     hbuf, sync, flags);
    k3_logits<<<128, 256, 0, stream>>>(hbuf, wfc, bfc, emb, d_out);
}

// Round 6
// 3720.402 us; speedup vs baseline: 1.0205x; 1.0205x over previous
//
#include <hip/hip_runtime.h>
#include <stdint.h>

// LSTMClassifier on MI355X — round 18: 32x32x16 MFMA, half the LDS traffic.
// R17 post-mortem: VGPR=84 — compiler AGAIN sank B-loads (lesson: weight
// residency must be structural, i.e. LDS; the allocator will not hold big
// arrays across a 512-iter loop). Reverting to R16 skeleton (best, 2.50ms)
// and fixing its two measured costs:
//  (1) B-frag LDS traffic (384 ds_read_b128/step/CU): switch to
//      mfma_f32_32x32x16_bf16 — 2x MACs per fragment byte -> 192 reads/step.
//  (2) SQ_LDS_BANK_CONFLICT 9.4M (xbuf lane-stride 64B): new exchange layout
//      [wave][reg-group][lane][4 f32] -> lane-dense floatx4 bursts, plus
//      scalar epilogue gathers at worst 4-way (~free per bank-conflict data).
// Wave w=(bt,ct,kh): batch-tile 32 rows, gate-pair 32 cols, K-half 384.
// Both K-halves have 8 pre-poll e-chunks (poll hidden on every SIMD).
// Epilogue split over all 512 threads (2 cells each), cre state per-thread.
// Sync skeleton identical to R15/R16 (proven): wave0 relaxed-agent poll,
// 3 barriers/step, one relaxed-agent publish, bounded RMW fallback.
//
// Workspace (50.6 MiB): unchanged layout.

#define EMB   256
#define HID   512
#define NOUT  18
#define BATCH 64
#define SEQ   512
#define NPART 32     // scan workgroups = CUs on one XCD
#define WCOLS 16     // h-cols per wg (512/32)
#define NKC   48     // K chunks of 16: 16 e + 32 h

typedef __attribute__((ext_vector_type(8)))  short bf16x8;
typedef __attribute__((ext_vector_type(4)))  float floatx4;
typedef __attribute__((ext_vector_type(16))) float f32x16;

__device__ inline float bf2f(short u) {
    union { float f; uint32_t i; } v;
    v.i = ((uint32_t)(uint16_t)u) << 16;
    return v.f;
}
__device__ inline short f2bf(float f) {
    union { float f; uint32_t i; } v; v.f = f;
    uint32_t r = v.i + 0x7fffu + ((v.i >> 16) & 1u);   // RNE
    return (short)(r >> 16);
}
__device__ inline float sigm(float x) { return 1.f / (1.f + __expf(-x)); }
__device__ inline float tanh_fast(float x) {
    float xc = fminf(fmaxf(x, -15.f), 15.f);
    float e  = __expf(2.f * xc);
    return (e - 1.f) / (e + 1.f);
}

// Detect packed-bf16 vs fp32 float tensors (verified round 4 — keep).
__device__ inline bool detect_bf16(const void* emb_raw) {
    const uint32_t* w = (const uint32_t*)emb_raw;
    int votes = 0;
    #pragma unroll
    for (int i = 0; i < 8; i++) {
        uint32_t e = (w[i] >> 7) & 0xFFu;
        votes += (e >= 110u && e <= 135u) ? 1 : 0;
    }
    return votes >= 6;
}
__device__ inline float rd(const void* p, int idx, bool isbf) {
    return isbf ? bf2f(((const short*)p)[idx]) : ((const float*)p)[idx];
}

// load one 8-element bf16 fragment from a maybe-fp32 weight row
__device__ inline bf16x8 ldfrag(const void* base, size_t off, bool isbf) {
    if (isbf) return *(const bf16x8*)((const short*)base + off);
    const float* s = (const float*)base + off;
    bf16x8 v;
    #pragma unroll
    for (int j = 0; j < 8; j++) v[j] = f2bf(s[j]);
    return v;
}

// ---------------------------------------------------------------------------
// K0: e_seq[u][k] = emb[x[u&63][u>>6]][k] (bf16 out), u = s*64+b.
// ---------------------------------------------------------------------------
__global__ __launch_bounds__(256) void k0_gather(
    const int* __restrict__ x, const void* __restrict__ emb,
    short* __restrict__ eseq)
{
    const bool isbf = detect_bf16(emb);
    const int u0 = blockIdx.x * 32;
    #pragma unroll
    for (int it = 0; it < 4; it++) {
        int idx = it * 256 + threadIdx.x;          // 0..1023
        int u   = u0 + (idx >> 5);
        int ch  = (idx & 31) * 8;
        int tok = x[(u & 63) * SEQ + (u >> 6)];
        bf16x8 v;
        if (isbf) {
            v = *(const bf16x8*)((const short*)emb + (size_t)tok * EMB + ch);
        } else {
            const float* src = (const float*)emb + (size_t)tok * EMB + ch;
            #pragma unroll
            for (int j = 0; j < 8; j++) v[j] = f2bf(src[j]);
        }
        *(bf16x8*)(eseq + (size_t)u * EMB + ch) = v;
    }
}

// ---------------------------------------------------------------------------
// K2: intra-XCD persistent scan, 32x32x16 MFMA, weights in LDS (96KB).
// 32 wgs x 512 thr. Wave w: bt=w&1 (batch 32), ct=(w>>1)&1 (gate pair),
// kh=w>>2 (K half). All waves export accs; epilogue over all 512 threads.
// ---------------------------------------------------------------------------
__global__ __launch_bounds__(512, 2) void k2_lstm(
    const void* __restrict__ w_hh, const void* __restrict__ w_ih,
    const void* __restrict__ b_ih, const void* __restrict__ b_hh,
    const void* __restrict__ emb, const short* __restrict__ eseq,
    short* __restrict__ hbuf, int* __restrict__ sync, int* __restrict__ flags)
{
    // B frags: [ct(2)][kc(48)][lane(64)][8 bf16] = 96KB, per-wave dense reads
    __shared__ short lds_b[2 * NKC * 64 * 8];
    // acc exchange: [w(8)][rg(4)][lane(64)][4 f32] = 32KB, lane-dense bursts
    __shared__ float xbuf[8 * 4 * 64 * 4];
    __shared__ float biasl[64];
    __shared__ int   sh_slot;

    const int t = threadIdx.x;

    // ---- XCD leader claim (round-9/10 verified; startup only).
    // Pigeonhole: 8*31 = 248 < 256 grid => some XCD always reaches NPART. ----
    if (t == 0) {
        unsigned xcd;
        asm volatile("s_getreg_b32 %0, hwreg(HW_REG_XCC_ID)" : "=s"(xcd));
        xcd &= 7u;
        int c = atomicAdd(&sync[8 + xcd], 1);
        if (c == NPART - 1) atomicCAS(&sync[0], 0, (int)xcd + 1);
        int L;
        while ((L = atomicAdd(&sync[0], 0)) == 0)
            __builtin_amdgcn_s_sleep(8);
        sh_slot = (L == (int)xcd + 1 && c < NPART) ? c : -1;
    }
    __syncthreads();
    const int g = sh_slot;
    if (g < 0) return;

    const bool isbf = detect_bf16(emb);
    const int lane = t & 63;
    const int w    = t >> 6;        // 0..7
    const int bt   = w & 1;         // batch tile (rows bt*32..+32)
    const int ct   = (w >> 1) & 1;  // gate-pair tile (gates {2ct,2ct+1})
    const int kh   = w >> 2;        // K half
    const int hi8  = (lane >> 5) * 8;

    // ---- stage B fragments into LDS (bf16), once ----
    // item -> (cts, kc, ln). ln: col=ln&31 (gate-col in tile), hiw=ln>>5.
    for (int item = t; item < 2 * NKC * 64; item += 512) {
        int cts = item / (NKC * 64);
        int rem = item - cts * (NKC * 64);
        int kc  = rem >> 6;
        int ln  = rem & 63;
        int colw = ln & 31, hiw = ln >> 5;
        int gate = 2 * cts + (colw >> 4);
        size_t grow = (size_t)gate * HID + g * WCOLS + (colw & 15);
        bf16x8 v;
        if (kc < 16) v = ldfrag(w_ih, grow * EMB + (size_t)kc * 16 + hiw * 8, isbf);
        else         v = ldfrag(w_hh, grow * HID + (size_t)(kc - 16) * 16 + hiw * 8, isbf);
        *(bf16x8*)(lds_b + (size_t)item * 8) = v;
    }
    if (t < 64) {
        int grow = (t >> 4) * HID + g * WCOLS + (t & 15);
        biasl[t] = rd(b_ih, grow, isbf) + rd(b_hh, grow, isbf);
    }
    __syncthreads();

    // epilogue role: cells (eb, ec2), (eb, ec2+1)
    const int eb   = t >> 3;           // batch row 0..63
    const int ec2  = (t & 7) * 2;      // col pair base
    const int ebi  = eb & 31;
    const int er03 = ebi & 3;
    const int ehi  = (ebi >> 2) & 1;
    const int erg  = ebi >> 3;
    const int ebt  = eb >> 5;
    const float bI0 = biasl[ 0 + ec2], bI1 = biasl[ 0 + ec2 + 1];
    const float bF0 = biasl[16 + ec2], bF1 = biasl[16 + ec2 + 1];
    const float bG0 = biasl[32 + ec2], bG1 = biasl[32 + ec2 + 1];
    const float bO0 = biasl[48 + ec2], bO1 = biasl[48 + ec2 + 1];

    float cre[2] = {0.f, 0.f};

    const short* erow = eseq + (size_t)(bt * 32 + (lane & 31)) * EMB + hi8;
    const short* hrow = hbuf + (size_t)(bt * 32 + (lane & 31)) * HID + hi8;
    short*       hwp  = hbuf + (size_t)(BATCH * HID)
                      + (size_t)eb * HID + g * WCOLS + ec2;

#define LB(ctx, kc) (*(const bf16x8*)(lds_b + ((size_t)(((ctx) * NKC + (kc)) * 64 + lane)) * 8))

    // ---- scan ----
    for (int step = 0; step < SEQ; step++) {
        // pre-poll: this wave's 8 e-chunks (kh-split so BOTH halves have
        // pre-poll work -> poll latency hidden on every SIMD)
        bf16x8 ae[8];
        #pragma unroll
        for (int kc = 0; kc < 8; kc++)
            ae[kc] = *(const bf16x8*)(erow + (kh * 8 + kc) * 16);

        f32x16 acc = {0.f,0.f,0.f,0.f,0.f,0.f,0.f,0.f,
                      0.f,0.f,0.f,0.f,0.f,0.f,0.f,0.f};
        #pragma unroll
        for (int kc = 0; kc < 8; kc++)
            acc = __builtin_amdgcn_mfma_f32_32x32x16_bf16(
                      ae[kc], LB(ct, kh * 8 + kc), acc, 0, 0, 0);

        // wave0's lanes 0..31 poll the 32 producer flags (RELAXED agent =
        // sc1 L1-bypass, no buffer_inv). Other waves wait at the barrier.
        if (step > 0 && w == 0 && lane < NPART) {
            int* fp = flags + (size_t)step * 64 + lane;
            int iters = 0;
            while (__hip_atomic_load(fp, __ATOMIC_RELAXED,
                                     __HIP_MEMORY_SCOPE_AGENT) == 0) {
                if (++iters > 16384) {
                    while (atomicAdd(fp, 0) == 0)
                        __builtin_amdgcn_s_sleep(8);
                    break;
                }
            }
        }
        __builtin_amdgcn_sched_barrier(0);
        __syncthreads();       // h(step-1) published & in L2

        // this wave's 16 h-chunks, loads issued back-to-back
        bf16x8 ah[16];
        #pragma unroll
        for (int j = 0; j < 16; j++)
            ah[j] = *(const bf16x8*)(hrow + (kh * 16 + j) * 16);
        #pragma unroll
        for (int j = 0; j < 16; j++)
            acc = __builtin_amdgcn_mfma_f32_32x32x16_bf16(
                      ah[j], LB(ct, 16 + kh * 16 + j), acc, 0, 0, 0);

        // export acc: [w][rg][lane][4] — lane-dense floatx4, conflict-free
        {
            float* xb = xbuf + ((size_t)w * 4 * 64 + lane) * 4;
            #pragma unroll
            for (int rg = 0; rg < 4; rg++) {
                floatx4 v4 = { acc[rg * 4 + 0], acc[rg * 4 + 1],
                               acc[rg * 4 + 2], acc[rg * 4 + 3] };
                *(floatx4*)(xb + (size_t)rg * 64 * 4) = v4;
            }
        }
        __syncthreads();       // partials visible

        // epilogue: all 512 threads, 2 cells each.
        // cell (eb, c): gate gp lives in writer wave (ebt, gp>>1, kh), lane
        // (gp&1)*16 + c + 32*ehi, reg r03 of group erg. Sum kh=0 + kh=1.
        {
            float vals[2][4];
            #pragma unroll
            for (int cc = 0; cc < 2; cc++) {
                const int c = ec2 + cc;
                #pragma unroll
                for (int gp = 0; gp < 4; gp++) {
                    const int lw = (gp & 1) * 16 + c + 32 * ehi;
                    const int wA = ebt + 2 * (gp >> 1);
                    vals[cc][gp] =
                        xbuf[(((size_t)wA * 4 + erg) * 64 + lw) * 4 + er03] +
                        xbuf[(((size_t)(wA + 4) * 4 + erg) * 64 + lw) * 4 + er03];
                }
            }
            float i0 = sigm(vals[0][0] + bI0), i1 = sigm(vals[1][0] + bI1);
            float f0 = sigm(vals[0][1] + bF0), f1 = sigm(vals[1][1] + bF1);
            float g0 = tanh_fast(vals[0][2] + bG0), g1 = tanh_fast(vals[1][2] + bG1);
            float o0 = sigm(vals[0][3] + bO0), o1 = sigm(vals[1][3] + bO1);
            cre[0] = f0 * cre[0] + i0 * g0;
            cre[1] = f1 * cre[1] + i1 * g1;
            float h0 = o0 * tanh_fast(cre[0]);
            float h1 = o1 * tanh_fast(cre[1]);
            uint32_t pack = ((uint32_t)(uint16_t)f2bf(h1) << 16)
                          |  (uint32_t)(uint16_t)f2bf(h0);
            *(uint32_t*)hwp = pack;
        }

        // barrier drains every wave's vmcnt before s_barrier => all h-stores
        // committed to L2 when t0 publishes. Also fences xbuf reuse.
        __syncthreads();
        if (t == 0)
            __hip_atomic_store(flags + (size_t)(step + 1) * 64 + g, 1,
                               __ATOMIC_RELAXED, __HIP_MEMORY_SCOPE_AGENT);

        erow += (size_t)BATCH * EMB;
        hrow += (size_t)BATCH * HID;
        hwp  += (size_t)BATCH * HID;
    }
#undef LB
}

// ---------------------------------------------------------------------------
// K3: logits = h_seq * W_fc^T + b_fc -> log_softmax(18). One token per thread.
// ---------------------------------------------------------------------------
__global__ __launch_bounds__(256) void k3_logits(
    const short* __restrict__ hbuf, const void* __restrict__ w_fc,
    const void* __restrict__ b_fc, const void* __restrict__ emb,
    void* __restrict__ out)
{
    __shared__ float Wf[NOUT][516];
    const bool isbf = detect_bf16(emb);
    const int t = threadIdx.x;
    for (int idx = t; idx < NOUT * 64; idx += 256) {
        int o = idx >> 6, ch = (idx & 63) * 8;
        #pragma unroll
        for (int j = 0; j < 8; j++)
            Wf[o][ch + j] = rd(w_fc, o * HID + ch + j, isbf);
    }
    __syncthreads();

    int u = blockIdx.x * 256 + t;              // u = s*64+b
    const short* hp = hbuf + (size_t)(u + BATCH) * HID;

    float acc[NOUT];
    #pragma unroll
    for (int o = 0; o < NOUT; o++) acc[o] = rd(b_fc, o, isbf);

    for (int ch = 0; ch < HID; ch += 8) {
        bf16x8 h8 = *(const bf16x8*)(hp + ch);
        float hf[8];
        #pragma unroll
        for (int j = 0; j < 8; j++) hf[j] = bf2f(h8[j]);
        #pragma unroll
        for (int o = 0; o < NOUT; o++) {
            floatx4 wa = *(const floatx4*)&Wf[o][ch];
            floatx4 wb = *(const floatx4*)&Wf[o][ch + 4];
            acc[o] += hf[0] * wa[0] + hf[1] * wa[1] + hf[2] * wa[2] + hf[3] * wa[3]
                    + hf[4] * wb[0] + hf[5] * wb[1] + hf[6] * wb[2] + hf[7] * wb[3];
        }
    }

    float mx = acc[0];
    #pragma unroll
    for (int o = 1; o < NOUT; o++) mx = fmaxf(mx, acc[o]);
    float s = 0.f;
    #pragma unroll
    for (int o = 0; o < NOUT; o++) s += __expf(acc[o] - mx);
    float lse = mx + __logf(s);

    int b = u & 63, sq = u >> 6;
    size_t base = (size_t)b * (SEQ * NOUT) + (size_t)sq * NOUT;
    if (isbf) {
        short* op = (short*)out + base;
        #pragma unroll
        for (int o = 0; o < NOUT; o++) op[o] = f2bf(acc[o] - lse);
    } else {
        float* op = (float*)out + base;
        #pragma unroll
        for (int o = 0; o < NOUT; o++) op[o] = acc[o] - lse;
    }
}

// ---------------------------------------------------------------------------
extern "C" void kernel_launch(void* const* d_in, const int* in_sizes, int n_in,
                              void* d_out, int out_size, void* d_ws, size_t ws_size,
                              hipStream_t stream) {
    const int*  x   = (const int*)d_in[0];
    const void* emb = d_in[1];
    const void* wih = d_in[2];
    const void* whh = d_in[3];
    const void* bih = d_in[4];
    const void* bhh = d_in[5];
    const void* wfc = d_in[6];
    const void* bfc = d_in[7];

    char*  ws    = (char*)d_ws;
    int*   sync  = (int*)ws;
    int*   flags = (int*)(ws + 4096);
    const size_t flagsz = (size_t)(SEQ + 1) * 64 * sizeof(int);   // 131.3 KB
    short* hbuf  = (short*)(ws + 4096 + ((flagsz + 255) & ~(size_t)255));
    short* eseq  = (short*)((char*)hbuf + (size_t)(SEQ + 1) * BATCH * HID * 2);

    (void)hipMemsetAsync(sync, 0, 4096, stream);                    // claim
    (void)hipMemsetAsync(flags, 0, flagsz, stream);                 // flags = 0
    (void)hipMemsetAsync(hbuf, 0, (size_t)BATCH * HID * 2, stream); // h_0 = 0

    k0_gather<<<1024, 256, 0, stream>>>(x, emb, eseq);
    k2_lstm<<<256, 512, 0, stream>>>(whh, wih, bih, bhh, emb, eseq,
                                     hbuf, sync, flags);
    k3_logits<<<128, 256, 0, stream>>>(hbuf, wfc, bfc, emb, d_out);
}